// Round 4
// baseline (829.214 us; speedup 1.0000x reference)
//
#include <hip/hip_runtime.h>
#include <math.h>

constexpr int H_ = 1024;
constexpr int I_ = 2816;
constexpr int E_ = 8;
constexpr int T_ = 1024;
constexpr int SLAB = 256;   // max tokens per expert slab (cnt ~ Bin(1024,1/8): P(>256) ~ 1e-28)

typedef __bf16 bf16x8 __attribute__((ext_vector_type(8)));
typedef float f32x4 __attribute__((ext_vector_type(4)));

__device__ __forceinline__ ushort f2bf(float f) {
    uint32_t u = __float_as_uint(f);
    u += 0x7fff + ((u >> 16) & 1);   // RNE
    return (ushort)(u >> 16);
}
__device__ __forceinline__ uint pack2(float lo, float hi) {
    return (uint)f2bf(lo) | ((uint)f2bf(hi) << 16);
}

// ws: int counts[8]; int tlist[8*1024]; ushort xg[8*256*1024]; ushort act[8*256*2816]

__global__ __launch_bounds__(64) void router_kernel(const float* __restrict__ hidden,
                                                    const float* __restrict__ rw,
                                                    int* __restrict__ counts,
                                                    int* __restrict__ tlist) {
    const int t = blockIdx.x;
    const int lane = threadIdx.x;
    const float4* x = (const float4*)(hidden + (size_t)t * H_) + lane;
    float4 v[4];
#pragma unroll
    for (int j = 0; j < 4; j++) v[j] = x[j * 64];
    float acc[E_];
#pragma unroll
    for (int e = 0; e < E_; e++) {
        const float4* r = (const float4*)(rw + e * H_) + lane;
        float a = 0.f;
#pragma unroll
        for (int j = 0; j < 4; j++) {
            float4 rv = r[j * 64];
            a += v[j].x * rv.x + v[j].y * rv.y + v[j].z * rv.z + v[j].w * rv.w;
        }
        acc[e] = a;
    }
#pragma unroll
    for (int e = 0; e < E_; e++) {
#pragma unroll
        for (int off = 32; off >= 1; off >>= 1)
            acc[e] += __shfl_xor(acc[e], off, 64);
    }
    if (lane == 0) {
        int best = 0;
        float bv = acc[0];
#pragma unroll
        for (int e = 1; e < E_; e++)
            if (acc[e] > bv) { bv = acc[e]; best = e; }   // strict > : first max wins
        int pos = atomicAdd(&counts[best], 1);
        if (pos < T_) tlist[best * T_ + pos] = t;
    }
}

// Gather token rows into dense bf16 slabs, zero-pad to 128-multiple.
__global__ __launch_bounds__(64) void gather_kernel(const float* __restrict__ hidden,
                                                    const int* __restrict__ counts,
                                                    const int* __restrict__ tlist,
                                                    ushort* __restrict__ xg) {
    const int r = blockIdx.x;            // 0..2047
    const int e = r >> 8, slot = r & 255;
    int cnt = counts[e]; if (cnt > SLAB) cnt = SLAB;
    const int limit = ((cnt + 127) >> 7) << 7;
    if (slot >= limit) return;
    ushort* dst = xg + (size_t)r * H_;
    const int lane = threadIdx.x;
    if (slot < cnt) {
        const int tok = tlist[e * T_ + slot];
        const float4* src = (const float4*)(hidden + (size_t)tok * H_) + lane;
        uint2* d = (uint2*)dst + lane;
#pragma unroll
        for (int j = 0; j < 4; j++) {
            float4 v = src[j * 64];
            d[j * 64] = make_uint2(pack2(v.x, v.y), pack2(v.z, v.w));
        }
    } else {
        uint4* d = (uint4*)dst + lane;
        d[0]  = make_uint4(0u, 0u, 0u, 0u);
        d[64] = make_uint4(0u, 0u, 0u, 0u);
    }
}

// Phase A: per (expert, 32-wide I-tile): act[slot][i] = silu(g)*u.  M=128, BK=64, 2-deep pipeline.
__global__ __launch_bounds__(256, 3) void gateup_kernel(const ushort* __restrict__ xg,
                                                        const float* __restrict__ gate_w,
                                                        const float* __restrict__ up_w,
                                                        const int* __restrict__ counts,
                                                        ushort* __restrict__ act) {
    const int e  = blockIdx.y;
    const int i0 = blockIdx.x * 32;
    int cnt = counts[e]; if (cnt > SLAB) cnt = SLAB;
    const int mtiles = (cnt + 127) >> 7;
    const int tid = threadIdx.x;

    __shared__ ushort Xs[128 * 64];
    __shared__ ushort Gs[32 * 64];
    __shared__ ushort Us[32 * 64];

    const int wv = tid >> 6, lane = tid & 63, quad = lane >> 4, l15 = lane & 15;
    const int rsw = l15 & 7;

    // precomputed swizzled LDS store offsets
    int xsaddr[4];
#pragma unroll
    for (int p = 0; p < 4; p++) {
        int r = (tid >> 3) + 32 * p, c = tid & 7;
        xsaddr[p] = r * 64 + ((c ^ (r & 7)) << 3);
    }
    int wsaddr[2];
#pragma unroll
    for (int p = 0; p < 2; p++) {
        int r = (tid >> 4) + 16 * p, ch = (tid & 15) >> 1;
        wsaddr[p] = r * 64 + ((ch ^ (r & 7)) << 3) + (tid & 1) * 4;
    }

    const float* gbase = gate_w + (size_t)e * I_ * H_ + (size_t)(i0 + (tid >> 4)) * H_ + (tid & 15) * 4;
    const float* ubase = up_w   + (size_t)e * I_ * H_ + (size_t)(i0 + (tid >> 4)) * H_ + (tid & 15) * 4;

    for (int mt = 0; mt < mtiles; mt++) {
        const ushort* xbase = xg + ((size_t)(e * SLAB + mt * 128 + (tid >> 3))) * H_ + (tid & 7) * 8;

        f32x4 accg[2][2], accu[2][2];
#pragma unroll
        for (int mi = 0; mi < 2; mi++)
#pragma unroll
            for (int nj = 0; nj < 2; nj++) {
                accg[mi][nj] = (f32x4){0.f, 0.f, 0.f, 0.f};
                accu[mi][nj] = (f32x4){0.f, 0.f, 0.f, 0.f};
            }

        uint4 xv[2][4]; float4 gv[2][2], uv[2][2];
#pragma unroll
        for (int st = 0; st < 2; st++) {
            const int k0 = st * 64;
#pragma unroll
            for (int p = 0; p < 4; p++) xv[st][p] = *(const uint4*)(xbase + (size_t)p * 32 * H_ + k0);
#pragma unroll
            for (int p = 0; p < 2; p++) {
                gv[st][p] = *(const float4*)(gbase + (size_t)p * 16 * H_ + k0);
                uv[st][p] = *(const float4*)(ubase + (size_t)p * 16 * H_ + k0);
            }
        }

        const int NK = H_ / 64;   // 16
        for (int k = 0; k < NK; k++) {
            const int st = k & 1;
            __syncthreads();
#pragma unroll
            for (int p = 0; p < 4; p++) *(uint4*)&Xs[xsaddr[p]] = xv[st][p];
#pragma unroll
            for (int p = 0; p < 2; p++) {
                *(uint2*)&Gs[wsaddr[p]] = make_uint2(pack2(gv[st][p].x, gv[st][p].y), pack2(gv[st][p].z, gv[st][p].w));
                *(uint2*)&Us[wsaddr[p]] = make_uint2(pack2(uv[st][p].x, uv[st][p].y), pack2(uv[st][p].z, uv[st][p].w));
            }
            if (k + 2 < NK) {   // refill stage st for iter k+2 (2-iter in-flight window)
                const int kn = (k + 2) * 64;
#pragma unroll
                for (int p = 0; p < 4; p++) xv[st][p] = *(const uint4*)(xbase + (size_t)p * 32 * H_ + kn);
#pragma unroll
                for (int p = 0; p < 2; p++) {
                    gv[st][p] = *(const float4*)(gbase + (size_t)p * 16 * H_ + kn);
                    uv[st][p] = *(const float4*)(ubase + (size_t)p * 16 * H_ + kn);
                }
            }
            __syncthreads();
#pragma unroll
            for (int kk = 0; kk < 64; kk += 32) {
                const int cq = (kk >> 3) + quad;
                bf16x8 a[2], bg[2], bu[2];
#pragma unroll
                for (int nj = 0; nj < 2; nj++) {
                    int off = (nj * 16 + l15) * 64 + ((cq ^ rsw) << 3);
                    bg[nj] = *(const bf16x8*)&Gs[off];
                    bu[nj] = *(const bf16x8*)&Us[off];
                }
#pragma unroll
                for (int mi = 0; mi < 2; mi++)
                    a[mi] = *(const bf16x8*)&Xs[(wv * 32 + mi * 16 + l15) * 64 + ((cq ^ rsw) << 3)];
#pragma unroll
                for (int mi = 0; mi < 2; mi++)
#pragma unroll
                    for (int nj = 0; nj < 2; nj++) {
                        accg[mi][nj] = __builtin_amdgcn_mfma_f32_16x16x32_bf16(a[mi], bg[nj], accg[mi][nj], 0, 0, 0);
                        accu[mi][nj] = __builtin_amdgcn_mfma_f32_16x16x32_bf16(a[mi], bu[nj], accu[mi][nj], 0, 0, 0);
                    }
            }
        }

#pragma unroll
        for (int mi = 0; mi < 2; mi++)
#pragma unroll
            for (int r = 0; r < 4; r++) {
                int row = mt * 128 + wv * 32 + mi * 16 + quad * 4 + r;   // slot index
#pragma unroll
                for (int nj = 0; nj < 2; nj++) {
                    float g = accg[mi][nj][r], u = accu[mi][nj][r];
                    float s = g / (1.f + __expf(-g)) * u;
                    act[((size_t)e * SLAB + row) * I_ + i0 + nj * 16 + l15] = f2bf(s);
                }
            }
    }
}

// Phase B: per (expert, 16-wide H-tile): out[tok] = act_slab @ down_w^T.  M=128, K=I, BK=64.
__global__ __launch_bounds__(256, 4) void down_kernel(const ushort* __restrict__ act,
                                                      const float* __restrict__ down_w,
                                                      const int* __restrict__ counts,
                                                      const int* __restrict__ tlist,
                                                      float* __restrict__ out) {
    const int e  = blockIdx.y;
    const int h0 = blockIdx.x * 16;
    int cnt = counts[e]; if (cnt > SLAB) cnt = SLAB;
    const int mtiles = (cnt + 127) >> 7;
    const int tid = threadIdx.x;

    __shared__ ushort As[128 * 64];
    __shared__ ushort Ds[16 * 64];

    const int wv = tid >> 6, lane = tid & 63, quad = lane >> 4, l15 = lane & 15;
    const int rsw = l15 & 7;

    int asaddr[4];
#pragma unroll
    for (int p = 0; p < 4; p++) {
        int r = (tid >> 3) + 32 * p, c = tid & 7;
        asaddr[p] = r * 64 + ((c ^ (r & 7)) << 3);
    }
    int dsaddr;
    {
        int r = tid >> 4, ch = (tid & 15) >> 1;
        dsaddr = r * 64 + ((ch ^ (r & 7)) << 3) + (tid & 1) * 4;
    }

    const float* dbase = down_w + (size_t)e * H_ * I_ + (size_t)(h0 + (tid >> 4)) * I_ + (tid & 15) * 4;

    for (int mt = 0; mt < mtiles; mt++) {
        const ushort* abase = act + ((size_t)(e * SLAB + mt * 128 + (tid >> 3))) * I_ + (tid & 7) * 8;

        f32x4 acc[2];
        acc[0] = (f32x4){0.f, 0.f, 0.f, 0.f};
        acc[1] = (f32x4){0.f, 0.f, 0.f, 0.f};

        uint4 av[2][4]; float4 dv[2];
#pragma unroll
        for (int st = 0; st < 2; st++) {
            const int k0 = st * 64;
#pragma unroll
            for (int p = 0; p < 4; p++) av[st][p] = *(const uint4*)(abase + (size_t)p * 32 * I_ + k0);
            dv[st] = *(const float4*)(dbase + k0);
        }

        const int NK = I_ / 64;   // 44
        for (int k = 0; k < NK; k++) {
            const int st = k & 1;
            __syncthreads();
#pragma unroll
            for (int p = 0; p < 4; p++) *(uint4*)&As[asaddr[p]] = av[st][p];
            *(uint2*)&Ds[dsaddr] = make_uint2(pack2(dv[st].x, dv[st].y), pack2(dv[st].z, dv[st].w));
            if (k + 2 < NK) {
                const int kn = (k + 2) * 64;
#pragma unroll
                for (int p = 0; p < 4; p++) av[st][p] = *(const uint4*)(abase + (size_t)p * 32 * I_ + kn);
                dv[st] = *(const float4*)(dbase + kn);
            }
            __syncthreads();
#pragma unroll
            for (int kk = 0; kk < 64; kk += 32) {
                const int cq = (kk >> 3) + quad;
                bf16x8 b = *(const bf16x8*)&Ds[l15 * 64 + ((cq ^ rsw) << 3)];
#pragma unroll
                for (int mi = 0; mi < 2; mi++) {
                    bf16x8 a = *(const bf16x8*)&As[(wv * 32 + mi * 16 + l15) * 64 + ((cq ^ rsw) << 3)];
                    acc[mi] = __builtin_amdgcn_mfma_f32_16x16x32_bf16(a, b, acc[mi], 0, 0, 0);
                }
            }
        }

#pragma unroll
        for (int mi = 0; mi < 2; mi++)
#pragma unroll
            for (int r = 0; r < 4; r++) {
                int slot = mt * 128 + wv * 32 + mi * 16 + quad * 4 + r;
                if (slot < cnt) {
                    int tok = tlist[e * T_ + slot];
                    out[(size_t)tok * H_ + h0 + l15] = acc[mi][r];
                }
            }
    }
}

extern "C" void kernel_launch(void* const* d_in, const int* in_sizes, int n_in,
                              void* d_out, int out_size, void* d_ws, size_t ws_size,
                              hipStream_t stream) {
    const float* hidden = (const float*)d_in[0];
    const float* rw     = (const float*)d_in[1];
    const float* gate_w = (const float*)d_in[2];
    const float* up_w   = (const float*)d_in[3];
    const float* down_w = (const float*)d_in[4];
    float* out = (float*)d_out;

    int* counts = (int*)d_ws;
    int* tlist  = counts + E_;
    ushort* xg  = (ushort*)(tlist + E_ * T_);            // 4 MB
    ushort* act = xg + (size_t)E_ * SLAB * H_;           // 11.5 MB

    hipMemsetAsync(counts, 0, E_ * sizeof(int), stream);
    hipLaunchKernelGGL(router_kernel, dim3(T_), dim3(64), 0, stream, hidden, rw, counts, tlist);
    hipLaunchKernelGGL(gather_kernel, dim3(E_ * SLAB), dim3(64), 0, stream, hidden, counts, tlist, xg);
    hipLaunchKernelGGL(gateup_kernel, dim3(I_ / 32, E_), dim3(256), 0, stream,
                       xg, gate_w, up_w, counts, act);
    hipLaunchKernelGGL(down_kernel, dim3(H_ / 16, E_), dim3(256), 0, stream,
                       act, down_w, counts, tlist, out);
}

// Round 5
// 389.268 us; speedup vs baseline: 2.1302x; 2.1302x over previous
//
#include <hip/hip_runtime.h>
#include <math.h>

constexpr int H_ = 1024;
constexpr int I_ = 2816;
constexpr int E_ = 8;
constexpr int T_ = 1024;
constexpr int SLAB = 256;   // max tokens per expert slab

typedef __bf16 bf16x8 __attribute__((ext_vector_type(8)));
typedef float f32x4 __attribute__((ext_vector_type(4)));

__device__ __forceinline__ ushort f2bf(float f) {
    uint32_t u = __float_as_uint(f);
    u += 0x7fff + ((u >> 16) & 1);   // RNE
    return (ushort)(u >> 16);
}
__device__ __forceinline__ uint pack2(float lo, float hi) {
    return (uint)f2bf(lo) | ((uint)f2bf(hi) << 16);
}

// ws: int counts[8]; int tlist[8*1024]; ushort xg[8*256*1024]; ushort act[8*256*2816]

__global__ __launch_bounds__(64) void router_kernel(const float* __restrict__ hidden,
                                                    const float* __restrict__ rw,
                                                    int* __restrict__ counts,
                                                    int* __restrict__ tlist) {
    const int t = blockIdx.x;
    const int lane = threadIdx.x;
    const float4* x = (const float4*)(hidden + (size_t)t * H_) + lane;
    float4 v[4];
#pragma unroll
    for (int j = 0; j < 4; j++) v[j] = x[j * 64];
    float acc[E_];
#pragma unroll
    for (int e = 0; e < E_; e++) {
        const float4* r = (const float4*)(rw + e * H_) + lane;
        float a = 0.f;
#pragma unroll
        for (int j = 0; j < 4; j++) {
            float4 rv = r[j * 64];
            a += v[j].x * rv.x + v[j].y * rv.y + v[j].z * rv.z + v[j].w * rv.w;
        }
        acc[e] = a;
    }
#pragma unroll
    for (int e = 0; e < E_; e++) {
#pragma unroll
        for (int off = 32; off >= 1; off >>= 1)
            acc[e] += __shfl_xor(acc[e], off, 64);
    }
    if (lane == 0) {
        int best = 0;
        float bv = acc[0];
#pragma unroll
        for (int e = 1; e < E_; e++)
            if (acc[e] > bv) { bv = acc[e]; best = e; }   // strict > : first max wins
        int pos = atomicAdd(&counts[best], 1);
        if (pos < T_) tlist[best * T_ + pos] = t;
    }
}

__global__ __launch_bounds__(64) void gather_kernel(const float* __restrict__ hidden,
                                                    const int* __restrict__ counts,
                                                    const int* __restrict__ tlist,
                                                    ushort* __restrict__ xg) {
    const int r = blockIdx.x;            // 0..2047
    const int e = r >> 8, slot = r & 255;
    int cnt = counts[e]; if (cnt > SLAB) cnt = SLAB;
    const int limit = ((cnt + 127) >> 7) << 7;
    if (slot >= limit) return;
    ushort* dst = xg + (size_t)r * H_;
    const int lane = threadIdx.x;
    if (slot < cnt) {
        const int tok = tlist[e * T_ + slot];
        const float4* src = (const float4*)(hidden + (size_t)tok * H_) + lane;
        uint2* d = (uint2*)dst + lane;
#pragma unroll
        for (int j = 0; j < 4; j++) {
            float4 v = src[j * 64];
            d[j * 64] = make_uint2(pack2(v.x, v.y), pack2(v.z, v.w));
        }
    } else {
        uint4* d = (uint4*)dst + lane;
        d[0]  = make_uint4(0u, 0u, 0u, 0u);
        d[64] = make_uint4(0u, 0u, 0u, 0u);
    }
}

// ---------------- Phase A: gate+up, M=128, N=32 (G and U), BK=64 ----------------
__global__ __launch_bounds__(256, 3) void gateup_kernel(const ushort* __restrict__ xg,
                                                        const float* __restrict__ gate_w,
                                                        const float* __restrict__ up_w,
                                                        const int* __restrict__ counts,
                                                        ushort* __restrict__ act) {
    const int e  = blockIdx.y;
    const int i0 = blockIdx.x * 32;
    int cnt = counts[e]; if (cnt > SLAB) cnt = SLAB;
    const int mtiles = (cnt + 127) >> 7;
    const int tid = threadIdx.x;

    __shared__ ushort Xs[128 * 64];
    __shared__ ushort Gs[32 * 64];
    __shared__ ushort Us[32 * 64];

    const int wv = tid >> 6, lane = tid & 63, quad = lane >> 4, l15 = lane & 15;
    const int rsw = l15 & 7;
    const int phase0 = (blockIdx.x + 3 * blockIdx.y) & 15;   // channel-spread K phases

    // swizzled LDS store addresses
    int xsaddr[4];
#pragma unroll
    for (int p = 0; p < 4; p++) {
        int r = (tid >> 3) + 32 * p, c = tid & 7;
        xsaddr[p] = r * 64 + ((c ^ (r & 7)) << 3);
    }
    int wsaddr[2];
#pragma unroll
    for (int p = 0; p < 2; p++) {
        int r = (tid >> 4) + 16 * p, ch = (tid & 15) >> 1;
        wsaddr[p] = r * 64 + ((ch ^ (r & 7)) << 3) + (tid & 1) * 4;
    }

    const float* gbase = gate_w + (size_t)e * I_ * H_ + (size_t)(i0 + (tid >> 4)) * H_ + (tid & 15) * 4;
    const float* ubase = up_w   + (size_t)e * I_ * H_ + (size_t)(i0 + (tid >> 4)) * H_ + (tid & 15) * 4;

    for (int mt = 0; mt < mtiles; mt++) {
        const ushort* xbase = xg + ((size_t)(e * SLAB + mt * 128 + (tid >> 3))) * H_ + (tid & 7) * 8;

        f32x4 accg[2][2], accu[2][2];
#pragma unroll
        for (int mi = 0; mi < 2; mi++)
#pragma unroll
            for (int nj = 0; nj < 2; nj++) {
                accg[mi][nj] = (f32x4){0.f, 0.f, 0.f, 0.f};
                accu[mi][nj] = (f32x4){0.f, 0.f, 0.f, 0.f};
            }

        // two named register sets (NO dynamic indexing -> stays in VGPRs)
        uint4 xA0, xA1, xA2, xA3, xB0, xB1, xB2, xB3;
        float4 gA0, gA1, uA0, uA1, gB0, gB1, uB0, uB1;

#define LOAD_SETA(K) do { int k_ = (K); \
        xA0 = *(const uint4*)(xbase + (size_t)0 * 32 * H_ + k_); \
        xA1 = *(const uint4*)(xbase + (size_t)1 * 32 * H_ + k_); \
        xA2 = *(const uint4*)(xbase + (size_t)2 * 32 * H_ + k_); \
        xA3 = *(const uint4*)(xbase + (size_t)3 * 32 * H_ + k_); \
        gA0 = *(const float4*)(gbase + (size_t)0 * 16 * H_ + k_); \
        gA1 = *(const float4*)(gbase + (size_t)1 * 16 * H_ + k_); \
        uA0 = *(const float4*)(ubase + (size_t)0 * 16 * H_ + k_); \
        uA1 = *(const float4*)(ubase + (size_t)1 * 16 * H_ + k_); } while (0)
#define LOAD_SETB(K) do { int k_ = (K); \
        xB0 = *(const uint4*)(xbase + (size_t)0 * 32 * H_ + k_); \
        xB1 = *(const uint4*)(xbase + (size_t)1 * 32 * H_ + k_); \
        xB2 = *(const uint4*)(xbase + (size_t)2 * 32 * H_ + k_); \
        xB3 = *(const uint4*)(xbase + (size_t)3 * 32 * H_ + k_); \
        gB0 = *(const float4*)(gbase + (size_t)0 * 16 * H_ + k_); \
        gB1 = *(const float4*)(gbase + (size_t)1 * 16 * H_ + k_); \
        uB0 = *(const float4*)(ubase + (size_t)0 * 16 * H_ + k_); \
        uB1 = *(const float4*)(ubase + (size_t)1 * 16 * H_ + k_); } while (0)
#define STORE_SET(x0,x1,x2,x3,g0,g1,u0,u1) do { \
        *(uint4*)&Xs[xsaddr[0]] = x0; *(uint4*)&Xs[xsaddr[1]] = x1; \
        *(uint4*)&Xs[xsaddr[2]] = x2; *(uint4*)&Xs[xsaddr[3]] = x3; \
        *(uint2*)&Gs[wsaddr[0]] = make_uint2(pack2(g0.x, g0.y), pack2(g0.z, g0.w)); \
        *(uint2*)&Gs[wsaddr[1]] = make_uint2(pack2(g1.x, g1.y), pack2(g1.z, g1.w)); \
        *(uint2*)&Us[wsaddr[0]] = make_uint2(pack2(u0.x, u0.y), pack2(u0.z, u0.w)); \
        *(uint2*)&Us[wsaddr[1]] = make_uint2(pack2(u1.x, u1.y), pack2(u1.z, u1.w)); } while (0)
#define MFMA_PHASE() do { \
        _Pragma("unroll") \
        for (int kk = 0; kk < 64; kk += 32) { \
            const int cq = (kk >> 3) + quad; \
            bf16x8 a_[2], bg_[2], bu_[2]; \
            _Pragma("unroll") \
            for (int nj = 0; nj < 2; nj++) { \
                int off = (nj * 16 + l15) * 64 + ((cq ^ rsw) << 3); \
                bg_[nj] = *(const bf16x8*)&Gs[off]; \
                bu_[nj] = *(const bf16x8*)&Us[off]; \
            } \
            _Pragma("unroll") \
            for (int mi = 0; mi < 2; mi++) \
                a_[mi] = *(const bf16x8*)&Xs[(wv * 32 + mi * 16 + l15) * 64 + ((cq ^ rsw) << 3)]; \
            _Pragma("unroll") \
            for (int mi = 0; mi < 2; mi++) \
                _Pragma("unroll") \
                for (int nj = 0; nj < 2; nj++) { \
                    accg[mi][nj] = __builtin_amdgcn_mfma_f32_16x16x32_bf16(a_[mi], bg_[nj], accg[mi][nj], 0, 0, 0); \
                    accu[mi][nj] = __builtin_amdgcn_mfma_f32_16x16x32_bf16(a_[mi], bu_[nj], accu[mi][nj], 0, 0, 0); \
                } \
        } } while (0)

        const int NK = H_ / 64;   // 16, power of 2
        LOAD_SETA(((0 + phase0) & 15) << 6);
        LOAD_SETB(((1 + phase0) & 15) << 6);
        for (int it = 0; it < NK; it += 2) {
            __syncthreads();
            STORE_SET(xA0, xA1, xA2, xA3, gA0, gA1, uA0, uA1);
            __syncthreads();
            if (it + 2 < NK) LOAD_SETA(((it + 2 + phase0) & 15) << 6);
            MFMA_PHASE();
            __syncthreads();
            STORE_SET(xB0, xB1, xB2, xB3, gB0, gB1, uB0, uB1);
            __syncthreads();
            if (it + 3 < NK) LOAD_SETB(((it + 3 + phase0) & 15) << 6);
            MFMA_PHASE();
        }
#undef LOAD_SETA
#undef LOAD_SETB
#undef STORE_SET
#undef MFMA_PHASE

#pragma unroll
        for (int mi = 0; mi < 2; mi++)
#pragma unroll
            for (int r = 0; r < 4; r++) {
                int row = mt * 128 + wv * 32 + mi * 16 + quad * 4 + r;   // slot index
#pragma unroll
                for (int nj = 0; nj < 2; nj++) {
                    float g = accg[mi][nj][r], u = accu[mi][nj][r];
                    float s = g / (1.f + __expf(-g)) * u;
                    act[((size_t)e * SLAB + row) * I_ + i0 + nj * 16 + l15] = f2bf(s);
                }
            }
    }
}

// ---------------- Phase B: down, M=128, N=16, K=I, BK=64 ----------------
__global__ __launch_bounds__(256, 4) void down_kernel(const ushort* __restrict__ act,
                                                      const float* __restrict__ down_w,
                                                      const int* __restrict__ counts,
                                                      const int* __restrict__ tlist,
                                                      float* __restrict__ out) {
    const int e  = blockIdx.y;
    const int h0 = blockIdx.x * 16;
    int cnt = counts[e]; if (cnt > SLAB) cnt = SLAB;
    const int mtiles = (cnt + 127) >> 7;
    const int tid = threadIdx.x;

    __shared__ ushort As[128 * 64];
    __shared__ ushort Ds[16 * 64];

    const int wv = tid >> 6, lane = tid & 63, quad = lane >> 4, l15 = lane & 15;
    const int rsw = l15 & 7;
    const int NK = I_ / 64;   // 44
    int phase0 = (blockIdx.x * 5 + blockIdx.y * 11) % NK;

    int asaddr[4];
#pragma unroll
    for (int p = 0; p < 4; p++) {
        int r = (tid >> 3) + 32 * p, c = tid & 7;
        asaddr[p] = r * 64 + ((c ^ (r & 7)) << 3);
    }
    int dsaddr;
    {
        int r = tid >> 4, ch = (tid & 15) >> 1;
        dsaddr = r * 64 + ((ch ^ (r & 7)) << 3) + (tid & 1) * 4;
    }

    const float* dbase = down_w + (size_t)e * H_ * I_ + (size_t)(h0 + (tid >> 4)) * I_ + (tid & 15) * 4;

    for (int mt = 0; mt < mtiles; mt++) {
        const ushort* abase = act + ((size_t)(e * SLAB + mt * 128 + (tid >> 3))) * I_ + (tid & 7) * 8;

        f32x4 acc0 = (f32x4){0.f, 0.f, 0.f, 0.f};
        f32x4 acc1 = (f32x4){0.f, 0.f, 0.f, 0.f};

        uint4 aA0, aA1, aA2, aA3, aB0, aB1, aB2, aB3;
        float4 dA, dB;

#define KOFS(IT) ({ int s_ = (IT) + phase0; if (s_ >= NK) s_ -= NK; if (s_ >= NK) s_ -= NK; s_ << 6; })
#define LOAD_SETA(K) do { int k_ = (K); \
        aA0 = *(const uint4*)(abase + (size_t)0 * 32 * I_ + k_); \
        aA1 = *(const uint4*)(abase + (size_t)1 * 32 * I_ + k_); \
        aA2 = *(const uint4*)(abase + (size_t)2 * 32 * I_ + k_); \
        aA3 = *(const uint4*)(abase + (size_t)3 * 32 * I_ + k_); \
        dA  = *(const float4*)(dbase + k_); } while (0)
#define LOAD_SETB(K) do { int k_ = (K); \
        aB0 = *(const uint4*)(abase + (size_t)0 * 32 * I_ + k_); \
        aB1 = *(const uint4*)(abase + (size_t)1 * 32 * I_ + k_); \
        aB2 = *(const uint4*)(abase + (size_t)2 * 32 * I_ + k_); \
        aB3 = *(const uint4*)(abase + (size_t)3 * 32 * I_ + k_); \
        dB  = *(const float4*)(dbase + k_); } while (0)
#define STORE_SET(a0,a1,a2,a3,dv) do { \
        *(uint4*)&As[asaddr[0]] = a0; *(uint4*)&As[asaddr[1]] = a1; \
        *(uint4*)&As[asaddr[2]] = a2; *(uint4*)&As[asaddr[3]] = a3; \
        *(uint2*)&Ds[dsaddr] = make_uint2(pack2(dv.x, dv.y), pack2(dv.z, dv.w)); } while (0)
#define MFMA_PHASE() do { \
        _Pragma("unroll") \
        for (int kk = 0; kk < 64; kk += 32) { \
            const int cq = (kk >> 3) + quad; \
            bf16x8 b_ = *(const bf16x8*)&Ds[l15 * 64 + ((cq ^ rsw) << 3)]; \
            bf16x8 a0_ = *(const bf16x8*)&As[(wv * 32 +      l15) * 64 + ((cq ^ rsw) << 3)]; \
            bf16x8 a1_ = *(const bf16x8*)&As[(wv * 32 + 16 + l15) * 64 + ((cq ^ rsw) << 3)]; \
            acc0 = __builtin_amdgcn_mfma_f32_16x16x32_bf16(a0_, b_, acc0, 0, 0, 0); \
            acc1 = __builtin_amdgcn_mfma_f32_16x16x32_bf16(a1_, b_, acc1, 0, 0, 0); \
        } } while (0)

        LOAD_SETA(KOFS(0));
        LOAD_SETB(KOFS(1));
        for (int it = 0; it < NK; it += 2) {
            __syncthreads();
            STORE_SET(aA0, aA1, aA2, aA3, dA);
            __syncthreads();
            if (it + 2 < NK) LOAD_SETA(KOFS(it + 2));
            MFMA_PHASE();
            __syncthreads();
            STORE_SET(aB0, aB1, aB2, aB3, dB);
            __syncthreads();
            if (it + 3 < NK) LOAD_SETB(KOFS(it + 3));
            MFMA_PHASE();
        }
#undef KOFS
#undef LOAD_SETA
#undef LOAD_SETB
#undef STORE_SET
#undef MFMA_PHASE

#pragma unroll
        for (int r = 0; r < 4; r++) {
            int slot0 = mt * 128 + wv * 32 + quad * 4 + r;
            if (slot0 < cnt) {
                int tok = tlist[e * T_ + slot0];
                out[(size_t)tok * H_ + h0 + l15] = acc0[r];
            }
            int slot1 = slot0 + 16;
            if (slot1 < cnt) {
                int tok = tlist[e * T_ + slot1];
                out[(size_t)tok * H_ + h0 + l15] = acc1[r];
            }
        }
    }
}

extern "C" void kernel_launch(void* const* d_in, const int* in_sizes, int n_in,
                              void* d_out, int out_size, void* d_ws, size_t ws_size,
                              hipStream_t stream) {
    const float* hidden = (const float*)d_in[0];
    const float* rw     = (const float*)d_in[1];
    const float* gate_w = (const float*)d_in[2];
    const float* up_w   = (const float*)d_in[3];
    const float* down_w = (const float*)d_in[4];
    float* out = (float*)d_out;

    int* counts = (int*)d_ws;
    int* tlist  = counts + E_;
    ushort* xg  = (ushort*)(tlist + E_ * T_);            // 4 MB
    ushort* act = xg + (size_t)E_ * SLAB * H_;           // 11.5 MB

    hipMemsetAsync(counts, 0, E_ * sizeof(int), stream);
    hipLaunchKernelGGL(router_kernel, dim3(T_), dim3(64), 0, stream, hidden, rw, counts, tlist);
    hipLaunchKernelGGL(gather_kernel, dim3(E_ * SLAB), dim3(64), 0, stream, hidden, counts, tlist, xg);
    hipLaunchKernelGGL(gateup_kernel, dim3(I_ / 32, E_), dim3(256), 0, stream,
                       xg, gate_w, up_w, counts, act);
    hipLaunchKernelGGL(down_kernel, dim3(H_ / 16, E_), dim3(256), 0, stream,
                       act, down_w, counts, tlist, out);
}